// Round 11
// baseline (233.158 us; speedup 1.0000x reference)
//
#include <hip/hip_runtime.h>
#include <hip/hip_bf16.h>

using bf16 = __hip_bfloat16;
typedef __bf16 bf16x8_t __attribute__((ext_vector_type(8)));
typedef float f32x4_t __attribute__((ext_vector_type(4)));
typedef float f32x16_t __attribute__((ext_vector_type(16)));

// ---------------------------------------------------------------- helpers
__device__ __forceinline__ void gl16(bf16* l, const bf16* g) {
  // async global->LDS, 16B per lane; LDS dest must be linear (base + lane*16)
  __builtin_amdgcn_global_load_lds(
      (const __attribute__((address_space(1))) unsigned int*)g,
      (__attribute__((address_space(3))) unsigned int*)l, 16, 0, 0);
}

#define BARRIER() do { asm volatile("" ::: "memory"); __builtin_amdgcn_s_barrier(); asm volatile("" ::: "memory"); } while (0)
#define WAITVM(N) asm volatile("s_waitcnt vmcnt(" #N ")" ::: "memory")
#define SCHED0() __builtin_amdgcn_sched_barrier(0)

// ---------------------------------------------------------------- fused prep: cvt x + transpose both W
__global__ __launch_bounds__(256) void prep_fused(const float* __restrict__ x,
                                                  const float* __restrict__ Wqkv,
                                                  const float* __restrict__ Wout,
                                                  bf16* __restrict__ xb,
                                                  bf16* __restrict__ w1t,
                                                  bf16* __restrict__ w2t) {
  __shared__ float t[32][33];
  const int bid = blockIdx.x;
  if (bid < 16384) {  // cvt: 4 f32 per thread
    int i = bid * 256 + threadIdx.x;
    float4 v = ((const float4*)x)[i];
    union { ushort4 u; bf16 b[4]; } o;
    o.b[0] = __float2bfloat16(v.x);
    o.b[1] = __float2bfloat16(v.y);
    o.b[2] = __float2bfloat16(v.z);
    o.b[3] = __float2bfloat16(v.w);
    ((ushort4*)xb)[i] = o.u;
    return;
  }
  const float* in; bf16* out; int R, C, gx, gy;
  if (bid < 16384 + 3072) {
    int idx = bid - 16384; in = Wqkv; out = w1t; R = 1024; C = 3072;
    gx = idx % 96; gy = idx / 96;
  } else {
    int idx = bid - 16384 - 3072; in = Wout; out = w2t; R = 1024; C = 1024;
    gx = idx & 31; gy = idx >> 5;
  }
  int bx = gx * 32, by = gy * 32;
  int tx = threadIdx.x & 31, ty = threadIdx.x >> 5;  // ty 0..7
#pragma unroll
  for (int r = 0; r < 32; r += 8)
    t[ty + r][tx] = in[(size_t)(by + ty + r) * C + bx + tx];
  __syncthreads();
#pragma unroll
  for (int r = 0; r < 32; r += 8)
    out[(size_t)(bx + ty + r) * R + by + tx] = __float2bfloat16(t[tx][ty + r]);
}

// ---------------------------------------------------------------- 256x256 bf16 GEMM, R5 persistent frame + 32x32x16 MFMA
// C[M=16384, N=NWGX*256] = A @ Bt^T + bias. K=1024 (16 K-steps of BK=64/tile), grid 256x512.
// LDS: 2 bufs x {Ah0,Ah1,Bh0,Bh1} halves of [128 rows][64 cols] bf16. Swizzle: 8-elem chunk
// index ^= row&7 on ds_read; inverse pre-applied on staging global source (LDS dest linear).
// Schedule = R5 (verified twice): 4 phases/K-step, 1 barrier each; fragment sets read one
// phase ahead of use; ph4 stages B(g+2,h0) then WAITVM(4) -> step g+1 fully resident.
// Compute core: mfma_f32_32x32x16_bf16. A frag: row=lane&31, k=(lane>>5)*8+j; per A-half H:
// LDS row R = wr*64 + am*32 + (lane&31). B frag: col=lane&31 -> R = wc*32 + (lane&31).
// acc[4][2] f32x16; C/D: col=lane&31, row=(reg&3)+8*(reg>>2)+4*(lane>>5)  [m74/m101].

__device__ __forceinline__ void readA32(const bf16* cb, int H, int wr, int l31, int lg1,
                                        bf16x8_t (&af)[2][4]) {
  const bf16* ab = cb + H * 8192;
#pragma unroll
  for (int am = 0; am < 2; ++am) {
    int R = wr * 64 + am * 32 + l31;
    const bf16* rp = ab + R * 64;
    int sw = (R & 7);
#pragma unroll
    for (int ks = 0; ks < 4; ++ks)
      af[am][ks] = *(const bf16x8_t*)(rp + (((ks * 2 + lg1) ^ sw) << 3));
  }
}
__device__ __forceinline__ void readB32(const bf16* cb, int H, int wc, int l31, int lg1,
                                        bf16x8_t (&bfr)[4]) {
  const bf16* bb = cb + 16384 + H * 8192;
  int R = wc * 32 + l31;
  const bf16* rp = bb + R * 64;
  int sw = (R & 7);
#pragma unroll
  for (int ks = 0; ks < 4; ++ks)
    bfr[ks] = *(const bf16x8_t*)(rp + (((ks * 2 + lg1) ^ sw) << 3));
}

template <int MH, int NH>
__device__ __forceinline__ void mfma32(bf16x8_t (&af)[2][4], bf16x8_t (&bfr)[4],
                                       f32x16_t (&acc)[4][2]) {
  __builtin_amdgcn_s_setprio(1);
#pragma unroll
  for (int am = 0; am < 2; ++am)
#pragma unroll
    for (int ks = 0; ks < 4; ++ks)
      acc[MH * 2 + am][NH] = __builtin_amdgcn_mfma_f32_32x32x16_bf16(
          af[am][ks], bfr[ks], acc[MH * 2 + am][NH], 0, 0, 0);
  __builtin_amdgcn_s_setprio(0);
}

template <int OUT_BF16, int NWGX>
__global__ __launch_bounds__(512, 2) void gemm256p(const bf16* __restrict__ A,
                                                   const bf16* __restrict__ Bt,
                                                   const float* __restrict__ bias,
                                                   void* __restrict__ Cv) {
  constexpr int K = 1024;
  constexpr int N = NWGX * 256;
  constexpr int TT = NWGX / 4;     // output tiles per block (grid fixed at 256)
  constexpr int G = TT * 16;       // flattened K-steps (BK=64)
  constexpr int CPX = NWGX * 8;    // tiles per XCD chunk

  __shared__ __align__(16) bf16 lds[65536];  // 128 KiB: 2 bufs x 4 halves x 8192 elems
  const int tid = threadIdx.x;
  const int bx = blockIdx.x;

  const int wid = tid >> 6, lane = tid & 63;
  const int wr = wid >> 2, wc = wid & 3;
  const int l31 = lane & 31, lg1 = lane >> 5;

  const int srow = tid >> 3;
  const int colg = ((((tid & 7) * 16) ^ ((srow & 7) << 4)) >> 1);
  const int browc0 = (srow >> 5) * 64 + (srow & 31);

  auto tileMN = [&](int tt, int& m0, int& n0) {
    int orig = bx + (tt << 8);
    int swz = (orig & 7) * CPX + (orig >> 3);
    m0 = (swz / NWGX) * 256;
    n0 = (swz % NWGX) * 256;
  };

  auto stageA = [&](int g, int h) {
    if (g >= G) return;
    int m0, n0; tileMN(g >> 4, m0, n0);
    const bf16* g0 = A + (size_t)(m0 + h * 64 + srow) * K + (g & 15) * 64 + colg;
    bf16* l = lds + (g & 1) * 32768 + h * 8192 + tid * 8;
    gl16(l, g0); gl16(l + 4096, g0 + (size_t)128 * K);
  };
  auto stageB = [&](int g, int h) {
    if (g >= G) return;
    int m0, n0; tileMN(g >> 4, m0, n0);
    const bf16* g0 = Bt + (size_t)(n0 + browc0 + h * 32) * K + (g & 15) * 64 + colg;
    bf16* l = lds + (g & 1) * 32768 + (2 + h) * 8192 + tid * 8;
    gl16(l, g0); gl16(l + 4096, g0 + (size_t)128 * K);
  };

  f32x16_t acc[4][2] = {};
  bf16x8_t af1[2][4], af2[2][4], b0[4], b1[4];

  // prologue: step 0 fully staged + {Ah0,Bh0}(1) in flight
  stageA(0, 0); stageB(0, 0); stageA(0, 1); stageB(0, 1);
  stageA(1, 0); stageB(1, 0);
  WAITVM(4);
  BARRIER();
  readA32(lds, 0, wr, l31, lg1, af1);   // A(0) MH=0
  readB32(lds, 0, wc, l31, lg1, b0);    // B(0) NH=0

  for (int g = 0; g < G; ++g) {
    const bf16* cb = lds + (g & 1) * 32768;
    const bf16* nb = lds + ((g & 1) ^ 1) * 32768;

    // phase 1: Q(0,0) = af1 x b0 ; read b1(g); stage A(g+1,h1)
    stageA(g + 1, 1);
    BARRIER();
    readB32(cb, 1, wc, l31, lg1, b1);
    SCHED0();
    mfma32<0, 0>(af1, b0, acc);

    // phase 2: Q(0,1) = af1 x b1 ; read af2(g); stage B(g+1,h1)
    stageB(g + 1, 1);
    BARRIER();
    readA32(cb, 1, wr, l31, lg1, af2);
    SCHED0();
    mfma32<0, 1>(af1, b1, acc);

    // phase 3: Q(1,0) = af2 x b0 ; stage A(g+2,h0)
    stageA(g + 2, 0);
    BARRIER();
    mfma32<1, 0>(af2, b0, acc);

    // phase 4: Q(1,1) = af2 x b1 ; stage B(g+2,h0); wait -> step g+1 resident
    stageB(g + 2, 0);
    if (g < G - 2) { WAITVM(4); } else { WAITVM(0); }
    BARRIER();
    if (g < G - 1) {
      readA32(nb, 0, wr, l31, lg1, af1);
      readB32(nb, 0, wc, l31, lg1, b0);
      SCHED0();
    }
    mfma32<1, 1>(af2, b1, acc);

    if ((g & 15) == 15) {
      BARRIER();  // keep dump stores out of the last phase's read window
      // dump finished tile; each wave-store covers a full 64B line (32 contiguous cols)
      int m0, n0; tileMN(g >> 4, m0, n0);
      float bv[2];
#pragma unroll
      for (int nh = 0; nh < 2; ++nh) bv[nh] = bias[n0 + wc * 64 + nh * 32 + l31];
#pragma unroll
      for (int a = 0; a < 4; ++a) {
        int rowb = m0 + wr * 128 + a * 32 + lg1 * 4;
#pragma unroll
        for (int reg = 0; reg < 16; ++reg) {
          int row = rowb + (reg & 3) + 8 * (reg >> 2);
#pragma unroll
          for (int nh = 0; nh < 2; ++nh) {
            int col = n0 + wc * 64 + nh * 32 + l31;
            float v = acc[a][nh][reg] + bv[nh];
            if (OUT_BF16)
              ((bf16*)Cv)[(size_t)row * N + col] = __float2bfloat16(v);
            else
              ((float*)Cv)[(size_t)row * N + col] = v;
            acc[a][nh][reg] = 0.f;
          }
        }
      }
    }
  }
}

// ---------------------------------------------------------------- per-token head-mixing attention (MFMA)
// qkv[t][0:1024]=q, [1024:2048]=k, [2048:3072]=v ; head layout idx = h*64+d
// logits[qh][kh] = 0.125 * dot(q[qh], k[kh]); softmax over kh; out[qh][d] = sum_kh p*v[kh][d]
#define PSTR 48
__global__ __launch_bounds__(256) void attn_tok(const bf16* __restrict__ qkv,
                                                bf16* __restrict__ out) {
  __shared__ __align__(16) bf16 vs[4][1024];
  __shared__ __align__(16) bf16 ps[4][16 * PSTR];
  const int w = threadIdx.x >> 6, l = threadIdx.x & 63;
  const int t = blockIdx.x * 4 + w;
  const int lr = l & 15, lg = l >> 4;
  const bf16* base = qkv + (size_t)t * 3072;

  bf16x8_t v0 = *(const bf16x8_t*)(base + 2048 + l * 16);
  bf16x8_t v1 = *(const bf16x8_t*)(base + 2048 + l * 16 + 8);
  *(bf16x8_t*)(&vs[w][l * 16]) = v0;
  *(bf16x8_t*)(&vs[w][l * 16 + 8]) = v1;

  *(unsigned long long*)(&ps[w][(l >> 2) * PSTR + 16 + (l & 3) * 4]) = 0ULL;

  const bf16* qp = base + lr * 64 + lg * 8;
  const bf16* kp = base + 1024 + lr * 64 + lg * 8;
  bf16x8_t qa0 = *(const bf16x8_t*)qp;
  bf16x8_t ka0 = *(const bf16x8_t*)kp;
  bf16x8_t qa1 = *(const bf16x8_t*)(qp + 32);
  bf16x8_t ka1 = *(const bf16x8_t*)(kp + 32);
  f32x4_t s = {};
  s = __builtin_amdgcn_mfma_f32_16x16x32_bf16(qa0, ka0, s, 0, 0, 0);
  s = __builtin_amdgcn_mfma_f32_16x16x32_bf16(qa1, ka1, s, 0, 0, 0);

#pragma unroll
  for (int j = 0; j < 4; ++j) {
    float x = s[j] * 0.125f;
    float mx = x;
#pragma unroll
    for (int off = 8; off; off >>= 1) mx = fmaxf(mx, __shfl_xor(mx, off, 16));
    float e = __expf(x - mx);
    float sum = e;
#pragma unroll
    for (int off = 8; off; off >>= 1) sum += __shfl_xor(sum, off, 16);
    ps[w][(lg * 4 + j) * PSTR + lr] = __float2bfloat16(e / sum);
  }

  bf16x8_t pf = *(const bf16x8_t*)(&ps[w][lr * PSTR + lg * 8]);
  bf16x8_t vf[4] = {};
  if (l < 32) {
#pragma unroll
    for (int c = 0; c < 4; ++c)
#pragma unroll
      for (int j = 0; j < 8; ++j)
        vf[c][j] = (__bf16)vs[w][(lg * 8 + j) * 64 + c * 16 + lr];
  }
  f32x4_t o[4] = {};
#pragma unroll
  for (int c = 0; c < 4; ++c)
    o[c] = __builtin_amdgcn_mfma_f32_16x16x32_bf16(pf, vf[c], o[c], 0, 0, 0);

  bf16* ob = out + (size_t)t * 1024;
#pragma unroll
  for (int c = 0; c < 4; ++c)
#pragma unroll
    for (int j = 0; j < 4; ++j)
      ob[(lg * 4 + j) * 64 + c * 16 + lr] = __float2bfloat16(o[c][j]);
}

// ---------------------------------------------------------------- launch
extern "C" void kernel_launch(void* const* d_in, const int* in_sizes, int n_in,
                              void* d_out, int out_size, void* d_ws, size_t ws_size,
                              hipStream_t stream) {
  const float* x    = (const float*)d_in[0];  // [16384,1024]
  const float* Wqkv = (const float*)d_in[1];  // [1024,3072]
  const float* bqkv = (const float*)d_in[2];  // [3072]
  const float* Wout = (const float*)d_in[3];  // [1024,1024]
  const float* bout = (const float*)d_in[4];  // [1024]
  float* y = (float*)d_out;                   // [16384,1024]

  const int T = 16384, HD = 1024, N1 = 3072;

  char* ws = (char*)d_ws;
  size_t off = 0;
  bf16* xb  = (bf16*)(ws + off); off += (size_t)T * HD * 2;
  bf16* w1t = (bf16*)(ws + off); off += (size_t)N1 * HD * 2;
  bf16* w2t = (bf16*)(ws + off); off += (size_t)HD * HD * 2;
  bf16* qkv = (bf16*)(ws + off); off += (size_t)T * N1 * 2;
  if (ws_size < off) return;
  bf16* ao = xb;  // xb dead after GEMM1; reuse as attention output

  prep_fused<<<16384 + 3072 + 1024, 256, 0, stream>>>(x, Wqkv, Wout, xb, w1t, w2t);
  gemm256p<1, 12><<<256, 512, 0, stream>>>(xb, w1t, bqkv, qkv);
  attn_tok<<<T / 4, 256, 0, stream>>>(qkv, ao);
  gemm256p<0, 4><<<256, 512, 0, stream>>>(ao, w2t, bout, y);
}

// Round 12
// 197.706 us; speedup vs baseline: 1.1793x; 1.1793x over previous
//
#include <hip/hip_runtime.h>
#include <hip/hip_bf16.h>

using bf16 = __hip_bfloat16;
typedef __bf16 bf16x8_t __attribute__((ext_vector_type(8)));
typedef float f32x4_t __attribute__((ext_vector_type(4)));

// ---------------------------------------------------------------- helpers
__device__ __forceinline__ void gl16(bf16* l, const bf16* g) {
  // async global->LDS, 16B per lane; LDS dest must be linear (base + lane*16)
  __builtin_amdgcn_global_load_lds(
      (const __attribute__((address_space(1))) unsigned int*)g,
      (__attribute__((address_space(3))) unsigned int*)l, 16, 0, 0);
}

#define BARRIER() do { asm volatile("" ::: "memory"); __builtin_amdgcn_s_barrier(); asm volatile("" ::: "memory"); } while (0)
#define WAITVM(N) asm volatile("s_waitcnt vmcnt(" #N ")" ::: "memory")

// ---------------------------------------------------------------- fused prep: cvt x + transpose both W
__global__ __launch_bounds__(256) void prep_fused(const float* __restrict__ x,
                                                  const float* __restrict__ Wqkv,
                                                  const float* __restrict__ Wout,
                                                  bf16* __restrict__ xb,
                                                  bf16* __restrict__ w1t,
                                                  bf16* __restrict__ w2t) {
  __shared__ float t[32][33];
  const int bid = blockIdx.x;
  if (bid < 16384) {  // cvt: 4 f32 per thread
    int i = bid * 256 + threadIdx.x;
    float4 v = ((const float4*)x)[i];
    union { ushort4 u; bf16 b[4]; } o;
    o.b[0] = __float2bfloat16(v.x);
    o.b[1] = __float2bfloat16(v.y);
    o.b[2] = __float2bfloat16(v.z);
    o.b[3] = __float2bfloat16(v.w);
    ((ushort4*)xb)[i] = o.u;
    return;
  }
  const float* in; bf16* out; int R, C, gx, gy;
  if (bid < 16384 + 3072) {
    int idx = bid - 16384; in = Wqkv; out = w1t; R = 1024; C = 3072;
    gx = idx % 96; gy = idx / 96;
  } else {
    int idx = bid - 16384 - 3072; in = Wout; out = w2t; R = 1024; C = 1024;
    gx = idx & 31; gy = idx >> 5;
  }
  int bx = gx * 32, by = gy * 32;
  int tx = threadIdx.x & 31, ty = threadIdx.x >> 5;  // ty 0..7
#pragma unroll
  for (int r = 0; r < 32; r += 8)
    t[ty + r][tx] = in[(size_t)(by + ty + r) * C + bx + tx];
  __syncthreads();
#pragma unroll
  for (int r = 0; r < 32; r += 8)
    out[(size_t)(bx + ty + r) * R + by + tx] = __float2bfloat16(t[tx][ty + r]);
}

// ---------------------------------------------------------------- 256x256 bf16 GEMM, R5 schedule (no sched_barrier pinning)
// C[M=16384, N=NWGX*256] = A @ Bt^T + bias. K=1024 (16 K-steps of BK=64), grid 256x512thr.
// LDS: 2 bufs x {Ah0,Ah1,Bh0,Bh1} halves of [128 rows][64 cols] bf16.
// 4 phases/K-step, 1 barrier each; fragment sets (af1,af2,b0,b1) read one phase AHEAD of
// use — reads and current-phase MFMAs are independent, and the compiler is free to
// interleave them (no sched_barrier!) so the LDS pipe overlaps the MFMA pipe.
// ph4 stages B(g+2,h0) then WAITVM(4) -> step g+1 fully resident.
// Swizzle: 8-elem chunk ^= row&7 on read; inverse pre-applied on staging global source.

__device__ __forceinline__ void readA(const bf16* lb, int half, int wr, int lr, int lg, int exr,
                                      bf16x8_t (&af)[4][2]) {
  const bf16* ab = lb + half * 8192;
#pragma unroll
  for (int mi = 0; mi < 4; ++mi) {
    int R = wr * 64 + mi * 16 + lr;
    af[mi][0] = *(const bf16x8_t*)(ab + R * 64 + ((lg * 8) ^ exr));
    af[mi][1] = *(const bf16x8_t*)(ab + R * 64 + ((32 + lg * 8) ^ exr));
  }
}
__device__ __forceinline__ void readB(const bf16* lb, int half, int wc, int lr, int lg, int exr,
                                      bf16x8_t (&bfr)[2][2]) {
  const bf16* bb = lb + (2 + half) * 8192;
#pragma unroll
  for (int ni = 0; ni < 2; ++ni) {
    int R = wc * 32 + ni * 16 + lr;
    bfr[ni][0] = *(const bf16x8_t*)(bb + R * 64 + ((lg * 8) ^ exr));
    bfr[ni][1] = *(const bf16x8_t*)(bb + R * 64 + ((32 + lg * 8) ^ exr));
  }
}

template <int MH, int NH>
__device__ __forceinline__ void mfma16(bf16x8_t (&af)[4][2], bf16x8_t (&bfr)[2][2],
                                       f32x4_t (&acc)[8][4]) {
  __builtin_amdgcn_s_setprio(1);
#pragma unroll
  for (int mi = 0; mi < 4; ++mi)
#pragma unroll
    for (int ni = 0; ni < 2; ++ni) {
      f32x4_t& a = acc[MH * 4 + mi][NH * 2 + ni];
      a = __builtin_amdgcn_mfma_f32_16x16x32_bf16(af[mi][0], bfr[ni][0], a, 0, 0, 0);
      a = __builtin_amdgcn_mfma_f32_16x16x32_bf16(af[mi][1], bfr[ni][1], a, 0, 0, 0);
    }
  __builtin_amdgcn_s_setprio(0);
}

template <int OUT_BF16, int NWGX>
__global__ __launch_bounds__(512, 2) void gemm256p(const bf16* __restrict__ A,
                                                   const bf16* __restrict__ Bt,
                                                   const float* __restrict__ bias,
                                                   void* __restrict__ Cv) {
  constexpr int K = 1024;
  constexpr int N = NWGX * 256;
  constexpr int TT = NWGX / 4;     // output tiles per block (grid fixed at 256)
  constexpr int G = TT * 16;       // flattened K-steps
  constexpr int CPX = NWGX * 8;    // tiles per XCD chunk

  __shared__ __align__(16) bf16 lds[65536];  // 128 KiB
  const int tid = threadIdx.x;
  const int bx = blockIdx.x;

  const int wid = tid >> 6, lane = tid & 63;
  const int wr = wid >> 2, wc = wid & 3;
  const int lr = lane & 15, lg = lane >> 4;
  const int exr = (lr & 7) << 3;

  const int srow = tid >> 3;
  const int colg = ((((tid & 7) * 16) ^ ((srow & 7) << 4)) >> 1);
  const int browc0 = (srow >> 5) * 64 + (srow & 31);

  auto tileMN = [&](int tt, int& m0, int& n0) {
    int orig = bx + (tt << 8);
    int swz = (orig & 7) * CPX + (orig >> 3);
    m0 = (swz / NWGX) * 256;
    n0 = (swz % NWGX) * 256;
  };

  auto stageA = [&](int g, int h) {
    if (g >= G) return;
    int m0, n0; tileMN(g >> 4, m0, n0);
    const bf16* g0 = A + (size_t)(m0 + h * 64 + srow) * K + (g & 15) * 64 + colg;
    bf16* l = lds + (g & 1) * 32768 + h * 8192 + tid * 8;
    gl16(l, g0); gl16(l + 4096, g0 + (size_t)128 * K);
  };
  auto stageB = [&](int g, int h) {
    if (g >= G) return;
    int m0, n0; tileMN(g >> 4, m0, n0);
    const bf16* g0 = Bt + (size_t)(n0 + browc0 + h * 32) * K + (g & 15) * 64 + colg;
    bf16* l = lds + (g & 1) * 32768 + (2 + h) * 8192 + tid * 8;
    gl16(l, g0); gl16(l + 4096, g0 + (size_t)128 * K);
  };

  f32x4_t acc[8][4] = {};
  bf16x8_t af1[4][2], af2[4][2], b0[2][2], b1[2][2];

  // prologue: K-step 0 fully staged + {Ah0,Bh0}(1) in flight
  stageA(0, 0); stageB(0, 0); stageA(0, 1); stageB(0, 1);
  stageA(1, 0); stageB(1, 0);
  WAITVM(4);
  BARRIER();
  readA(lds, 0, wr, lr, lg, exr, af1);   // Ah0(0)
  readB(lds, 0, wc, lr, lg, exr, b0);    // Bh0(0)

  for (int g = 0; g < G; ++g) {
    const bf16* cb = lds + (g & 1) * 32768;
    const bf16* nb = lds + ((g & 1) ^ 1) * 32768;

    // phase 1: Q(0,0) = af1 x b0 ; prefetch b1 (Bh1 cur)  [reads free to mix with MFMA]
    stageA(g + 1, 1);
    BARRIER();
    readB(cb, 1, wc, lr, lg, exr, b1);
    mfma16<0, 0>(af1, b0, acc);

    // phase 2: Q(0,1) = af1 x b1 ; prefetch af2 (Ah1 cur)
    stageB(g + 1, 1);
    BARRIER();
    readA(cb, 1, wr, lr, lg, exr, af2);
    mfma16<0, 1>(af1, b1, acc);

    // phase 3: Q(1,0) = af2 x b0
    stageA(g + 2, 0);
    BARRIER();
    mfma16<1, 0>(af2, b0, acc);

    // phase 4: Q(1,1) = af2 x b1 ; prefetch af1,b0 from NEXT buffer
    stageB(g + 2, 0);
    if (g < G - 2) { WAITVM(4); } else { WAITVM(0); }
    BARRIER();
    if (g < G - 1) {
      readA(nb, 0, wr, lr, lg, exr, af1);
      readB(nb, 0, wc, lr, lg, exr, b0);
    }
    mfma16<1, 1>(af2, b1, acc);

    if ((g & 15) == 15) {
      BARRIER();  // keep dump stores out of the last phase's read window
      // dump finished tile; n innermost so each 64B C-line completes back-to-back
      int m0, n0; tileMN(g >> 4, m0, n0);
      float bv[4];
#pragma unroll
      for (int n = 0; n < 4; ++n) bv[n] = bias[n0 + wc * 64 + n * 16 + lr];
#pragma unroll
      for (int m = 0; m < 8; ++m) {
        int row = m0 + wr * 128 + m * 16 + lg * 4;
#pragma unroll
        for (int j = 0; j < 4; ++j) {
#pragma unroll
          for (int n = 0; n < 4; ++n) {
            int col = n0 + wc * 64 + n * 16 + lr;
            float v = acc[m][n][j] + bv[n];
            if (OUT_BF16)
              ((bf16*)Cv)[(size_t)(row + j) * N + col] = __float2bfloat16(v);
            else
              ((float*)Cv)[(size_t)(row + j) * N + col] = v;
            acc[m][n][j] = 0.f;
          }
        }
      }
    }
  }
}

// ---------------------------------------------------------------- per-token head-mixing attention (MFMA)
// qkv[t][0:1024]=q, [1024:2048]=k, [2048:3072]=v ; head layout idx = h*64+d
// logits[qh][kh] = 0.125 * dot(q[qh], k[kh]); softmax over kh; out[qh][d] = sum_kh p*v[kh][d]
#define PSTR 48
__global__ __launch_bounds__(256) void attn_tok(const bf16* __restrict__ qkv,
                                                bf16* __restrict__ out) {
  __shared__ __align__(16) bf16 vs[4][1024];
  __shared__ __align__(16) bf16 ps[4][16 * PSTR];
  const int w = threadIdx.x >> 6, l = threadIdx.x & 63;
  const int t = blockIdx.x * 4 + w;
  const int lr = l & 15, lg = l >> 4;
  const bf16* base = qkv + (size_t)t * 3072;

  bf16x8_t v0 = *(const bf16x8_t*)(base + 2048 + l * 16);
  bf16x8_t v1 = *(const bf16x8_t*)(base + 2048 + l * 16 + 8);
  *(bf16x8_t*)(&vs[w][l * 16]) = v0;
  *(bf16x8_t*)(&vs[w][l * 16 + 8]) = v1;

  *(unsigned long long*)(&ps[w][(l >> 2) * PSTR + 16 + (l & 3) * 4]) = 0ULL;

  const bf16* qp = base + lr * 64 + lg * 8;
  const bf16* kp = base + 1024 + lr * 64 + lg * 8;
  bf16x8_t qa0 = *(const bf16x8_t*)qp;
  bf16x8_t ka0 = *(const bf16x8_t*)kp;
  bf16x8_t qa1 = *(const bf16x8_t*)(qp + 32);
  bf16x8_t ka1 = *(const bf16x8_t*)(kp + 32);
  f32x4_t s = {};
  s = __builtin_amdgcn_mfma_f32_16x16x32_bf16(qa0, ka0, s, 0, 0, 0);
  s = __builtin_amdgcn_mfma_f32_16x16x32_bf16(qa1, ka1, s, 0, 0, 0);

#pragma unroll
  for (int j = 0; j < 4; ++j) {
    float x = s[j] * 0.125f;
    float mx = x;
#pragma unroll
    for (int off = 8; off; off >>= 1) mx = fmaxf(mx, __shfl_xor(mx, off, 16));
    float e = __expf(x - mx);
    float sum = e;
#pragma unroll
    for (int off = 8; off; off >>= 1) sum += __shfl_xor(sum, off, 16);
    ps[w][(lg * 4 + j) * PSTR + lr] = __float2bfloat16(e / sum);
  }

  bf16x8_t pf = *(const bf16x8_t*)(&ps[w][lr * PSTR + lg * 8]);
  bf16x8_t vf[4] = {};
  if (l < 32) {
#pragma unroll
    for (int c = 0; c < 4; ++c)
#pragma unroll
      for (int j = 0; j < 8; ++j)
        vf[c][j] = (__bf16)vs[w][(lg * 8 + j) * 64 + c * 16 + lr];
  }
  f32x4_t o[4] = {};
#pragma unroll
  for (int c = 0; c < 4; ++c)
    o[c] = __builtin_amdgcn_mfma_f32_16x16x32_bf16(pf, vf[c], o[c], 0, 0, 0);

  bf16* ob = out + (size_t)t * 1024;
#pragma unroll
  for (int c = 0; c < 4; ++c)
#pragma unroll
    for (int j = 0; j < 4; ++j)
      ob[(lg * 4 + j) * 64 + c * 16 + lr] = __float2bfloat16(o[c][j]);
}

// ---------------------------------------------------------------- launch
extern "C" void kernel_launch(void* const* d_in, const int* in_sizes, int n_in,
                              void* d_out, int out_size, void* d_ws, size_t ws_size,
                              hipStream_t stream) {
  const float* x    = (const float*)d_in[0];  // [16384,1024]
  const float* Wqkv = (const float*)d_in[1];  // [1024,3072]
  const float* bqkv = (const float*)d_in[2];  // [3072]
  const float* Wout = (const float*)d_in[3];  // [1024,1024]
  const float* bout = (const float*)d_in[4];  // [1024]
  float* y = (float*)d_out;                   // [16384,1024]

  const int T = 16384, HD = 1024, N1 = 3072;

  char* ws = (char*)d_ws;
  size_t off = 0;
  bf16* xb  = (bf16*)(ws + off); off += (size_t)T * HD * 2;
  bf16* w1t = (bf16*)(ws + off); off += (size_t)N1 * HD * 2;
  bf16* w2t = (bf16*)(ws + off); off += (size_t)HD * HD * 2;
  bf16* qkv = (bf16*)(ws + off); off += (size_t)T * N1 * 2;
  if (ws_size < off) return;
  bf16* ao = xb;  // xb dead after GEMM1; reuse as attention output

  prep_fused<<<16384 + 3072 + 1024, 256, 0, stream>>>(x, Wqkv, Wout, xb, w1t, w2t);
  gemm256p<1, 12><<<256, 512, 0, stream>>>(xb, w1t, bqkv, qkv);
  attn_tok<<<T / 4, 256, 0, stream>>>(qkv, ao);
  gemm256p<0, 4><<<256, 512, 0, stream>>>(ao, w2t, bout, y);
}